// Round 11
// baseline (44.940 us; speedup 1.0000x reference)
//
#include <hip/hip_runtime.h>
#include <hip/hip_bf16.h>

// Problem constants (B, T, C, HS) from the reference.
#define NB 256
#define NT 256
#define NC 384
#define NH 64
#define NW 192              // 3 * NH concatenated output cols
#define WT_ELEMS (NW * NC)  // Wt2 bf16 elements = 73728

typedef short bf16x8 __attribute__((ext_vector_type(8)));
typedef float f32x4 __attribute__((ext_vector_type(4)));

__device__ __forceinline__ unsigned short f2bf(float f) {
  union { float f; unsigned int i; } c;
  c.f = f;
  const unsigned int r = c.i + 0x7fffu + ((c.i >> 16) & 1u);
  return (unsigned short)(r >> 16);
}

__device__ __forceinline__ unsigned short f2bf_hw(float f) {
  __hip_bfloat16 b = __float2bfloat16(f);
  return *reinterpret_cast<unsigned short*>(&b);
}

__device__ __forceinline__ bf16x8 cvt8(float4 lo, float4 hi) {
  union { bf16x8 v; unsigned short u[8]; } au;
  au.u[0] = f2bf_hw(lo.x); au.u[1] = f2bf_hw(lo.y);
  au.u[2] = f2bf_hw(lo.z); au.u[3] = f2bf_hw(lo.w);
  au.u[4] = f2bf_hw(hi.x); au.u[5] = f2bf_hw(hi.y);
  au.u[6] = f2bf_hw(hi.z); au.u[7] = f2bf_hw(hi.w);
  return au.v;
}

// ---------------------------------------------------------------------------
// Kernel 0: build FRAGMENT-MAJOR weights.
// Wt2[((kt*12 + ni)*64 + lane)*8 + j] = W_sel[k][h], where
//   n = ni*16 + (lane&15)  (sel/h by n),  k = kt*32 + (lane>>4)*8 + j.
// A wave's B-fragment load is then ONE coalesced 1 KB read:
//   bf16x8 at Wt2 + (kt*12+ni)*512 + lane*8.
// All waves/blocks read identical addresses -> L1/L2-hot.
// ---------------------------------------------------------------------------
__global__ __launch_bounds__(256) void w_prep_kernel(
    const float* __restrict__ Wq,
    const float* __restrict__ Wk,
    const float* __restrict__ Wv,
    unsigned short* __restrict__ Wt2) {
  const int o = blockIdx.x * 256 + threadIdx.x;
  if (o >= WT_ELEMS) return;
  const int j = o & 7;
  const int lane = (o >> 3) & 63;
  const int fi = o >> 9;            // 0..143 = kt*12 + ni
  const int ni = fi % 12;
  const int kt = fi / 12;
  const int n = ni * 16 + (lane & 15);
  const int k = kt * 32 + ((lane >> 4) << 3) + j;
  const float* W = (n < 64) ? Wq : (n < 128) ? Wk : Wv;
  Wt2[o] = f2bf(W[k * NH + (n & 63)]);
}

// ---------------------------------------------------------------------------
// Kernel 1 (round 11): fused proj+attn with BARRIER-FREE projection.
//
// Round-10 post-mortem: two different staging mechanisms (global_load_lds
// 3-deep vs reg-staged) both land ~2.2 us/step -> the limiter is the
// lockstep itself: all 8 waves barrier per k-tile, so each step costs the
// tile's fair-share transfer time plus burst-queuing, regardless of
// instrument. Structural fix: in proj, each wave reads only ITS OWN 32
// x-rows; only W is shared. Make W sharing-free via fragment-major Wt2
// (coalesced reg loads, L1-served redundancy) and load A-frags straight
// from x to registers (16 rows x one fully-consumed 128B line per instr).
// => proj has NO LDS, NO barriers, NO explicit waitcnt; waves drift and
// the compiler pipelines loads (#pragma unroll 2).
//
// Epilogue: one scatter of acc into attn LDS layouts + __syncthreads;
// attn phase unchanged from round 10 (verified).
// mfma_f32_16x16x32_bf16 layouts (HW-verified round 2):
//   A/B: k = (l>>4)*8+j contiguous;  D: n = l&15, m = (l>>4)*4 + r.
// ---------------------------------------------------------------------------
__global__ __launch_bounds__(512, 2) void fused_qkv_attn_kernel(
    const float* __restrict__ x,
    const unsigned short* __restrict__ Wt2,
    float* __restrict__ out) {
  __shared__ __align__(16) unsigned char lds[118784];

  const int tid = threadIdx.x;
  const int w = tid >> 6;
  const int lane = tid & 63;
  const int l15 = lane & 15;
  const int lg = lane >> 4;
  const int b = blockIdx.x;
  const int row0 = b * NT;              // this block's 256 x-rows
  const int qt = (w < 4) ? w : 11 - w;  // causal-balanced q-tile per wave
  const int wbase = qt * 32;            // wave's 32 rows (block-local)

  f32x4 acc[2][12];
#pragma unroll
  for (int mi = 0; mi < 2; ++mi)
#pragma unroll
    for (int ni = 0; ni < 12; ++ni)
#pragma unroll
      for (int r = 0; r < 4; ++r) acc[mi][ni][r] = 0.f;

  // ---- proj phase: barrier-free, register-only ----
  // Per-lane A base: row wbase+l15 (and +16), col base lg*8.
  const float* xa0 = x + (size_t)(row0 + wbase + l15) * NC + lg * 8;
  const float* xa1 = xa0 + (size_t)16 * NC;
  const unsigned short* wfrag = Wt2 + lane * 8;

#pragma unroll 2
  for (int kt = 0; kt < 12; ++kt) {
    const float4 a0lo = *reinterpret_cast<const float4*>(xa0 + kt * 32);
    const float4 a0hi = *reinterpret_cast<const float4*>(xa0 + kt * 32 + 4);
    const float4 a1lo = *reinterpret_cast<const float4*>(xa1 + kt * 32);
    const float4 a1hi = *reinterpret_cast<const float4*>(xa1 + kt * 32 + 4);
    const bf16x8 afr0 = cvt8(a0lo, a0hi);
    const bf16x8 afr1 = cvt8(a1lo, a1hi);
#pragma unroll
    for (int ni = 0; ni < 12; ++ni) {
      const bf16x8 bfr = *reinterpret_cast<const bf16x8*>(
          wfrag + (size_t)(kt * 12 + ni) * 512);
      acc[0][ni] = __builtin_amdgcn_mfma_f32_16x16x32_bf16(
          afr0, bfr, acc[0][ni], 0, 0, 0);
      acc[1][ni] = __builtin_amdgcn_mfma_f32_16x16x32_bf16(
          afr1, bfr, acc[1][ni], 0, 0, 0);
    }
  }

  // ---- epilogue: scatter acc into attention LDS layouts (bf16) ----
  unsigned short* Kls = reinterpret_cast<unsigned short*>(lds);           // 32K
  unsigned short* Vtls = reinterpret_cast<unsigned short*>(lds + 32768);  // 32K
  unsigned short* Qls = reinterpret_cast<unsigned short*>(lds + 65536);   // 32K
  unsigned short* Pls = reinterpret_cast<unsigned short*>(lds + 98304);   // 20K

#pragma unroll
  for (int mi = 0; mi < 2; ++mi)
#pragma unroll
    for (int ni = 0; ni < 12; ++ni) {
      const int n = ni * 16 + l15;
#pragma unroll
      for (int r = 0; r < 4; ++r) {
        const int srow = wbase + mi * 16 + lg * 4 + r;
        const unsigned short val = f2bf_hw(acc[mi][ni][r]);
        if (ni < 4) {
          Qls[srow * 64 + (n ^ ((srow & 7) << 3))] = val;
        } else if (ni < 8) {
          const int h = n - 64;
          Kls[srow * 64 + (h ^ ((srow & 7) << 3))] = val;
        } else {
          const int h = n - 128;
          Vtls[h * 256 + (srow ^ ((h & 7) << 3))] = val;
        }
      }
    }
  __syncthreads();

  // ---- attention phase (flash, per-wave independent; unchanged) ----
  const int q0 = wbase;
  bf16x8 a_q[2][2];
#pragma unroll
  for (int mi = 0; mi < 2; ++mi)
#pragma unroll
    for (int ks = 0; ks < 2; ++ks) {
      const int srow = q0 + mi * 16 + l15;
      a_q[mi][ks] = *reinterpret_cast<const bf16x8*>(
          Qls + srow * 64 + ((ks * 32 + lg * 8) ^ ((srow & 7) << 3)));
    }

  f32x4 o[2][4];
  float mrun[2][4], lrun[2][4];
#pragma unroll
  for (int mi = 0; mi < 2; ++mi)
#pragma unroll
    for (int r = 0; r < 4; ++r) {
      mrun[mi][r] = -3.0e38f;
      lrun[mi][r] = 0.f;
#pragma unroll
      for (int hi = 0; hi < 4; ++hi) o[mi][hi][r] = 0.f;
    }

  unsigned short* Pw = Pls + w * 1280;  // per-wave [32][40]

  for (int j = 0; j <= qt; ++j) {
    f32x4 s_acc[2][2];
#pragma unroll
    for (int mi = 0; mi < 2; ++mi)
#pragma unroll
      for (int si = 0; si < 2; ++si)
#pragma unroll
        for (int r = 0; r < 4; ++r) s_acc[mi][si][r] = 0.f;

#pragma unroll
    for (int ks = 0; ks < 2; ++ks) {
      bf16x8 bk[2];
#pragma unroll
      for (int si = 0; si < 2; ++si) {
        const int srow = j * 32 + si * 16 + l15;
        const int kel = ks * 32 + lg * 8;
        bk[si] = *reinterpret_cast<const bf16x8*>(
            Kls + srow * 64 + (kel ^ ((srow & 7) << 3)));
      }
#pragma unroll
      for (int mi = 0; mi < 2; ++mi)
#pragma unroll
        for (int si = 0; si < 2; ++si)
          s_acc[mi][si] = __builtin_amdgcn_mfma_f32_16x16x32_bf16(
              a_q[mi][ks], bk[si], s_acc[mi][si], 0, 0, 0);
    }

    const bool diag = (j == qt);
#pragma unroll
    for (int mi = 0; mi < 2; ++mi) {
#pragma unroll
      for (int r = 0; r < 4; ++r) {
        const int mloc = mi * 16 + lg * 4 + r;
        float v0 = s_acc[mi][0][r] * 0.125f;
        float v1 = s_acc[mi][1][r] * 0.125f;
        if (diag) {
          if (l15 > mloc) v0 = -3.0e38f;
          if (16 + l15 > mloc) v1 = -3.0e38f;
        }
        float pm = fmaxf(v0, v1);
        pm = fmaxf(pm, __shfl_xor(pm, 1, 16));
        pm = fmaxf(pm, __shfl_xor(pm, 2, 16));
        pm = fmaxf(pm, __shfl_xor(pm, 4, 16));
        pm = fmaxf(pm, __shfl_xor(pm, 8, 16));
        const float mnew = fmaxf(mrun[mi][r], pm);
        const float alpha = __expf(mrun[mi][r] - mnew);
        mrun[mi][r] = mnew;
        const float p0 = __expf(v0 - mnew);
        const float p1 = __expf(v1 - mnew);
        float ps = p0 + p1;
        ps += __shfl_xor(ps, 1, 16);
        ps += __shfl_xor(ps, 2, 16);
        ps += __shfl_xor(ps, 4, 16);
        ps += __shfl_xor(ps, 8, 16);
        lrun[mi][r] = lrun[mi][r] * alpha + ps;
#pragma unroll
        for (int hi = 0; hi < 4; ++hi) o[mi][hi][r] *= alpha;
        Pw[mloc * 40 + l15] = f2bf(p0);
        Pw[mloc * 40 + 16 + l15] = f2bf(p1);
      }
    }

    bf16x8 pa[2];
#pragma unroll
    for (int mt = 0; mt < 2; ++mt)
      pa[mt] = *reinterpret_cast<const bf16x8*>(
          Pw + (mt * 16 + l15) * 40 + lg * 8);
#pragma unroll
    for (int hi = 0; hi < 4; ++hi) {
      const int h = hi * 16 + l15;
      const int sel = j * 32 + lg * 8;
      const bf16x8 bv = *reinterpret_cast<const bf16x8*>(
          Vtls + h * 256 + (sel ^ ((h & 7) << 3)));
#pragma unroll
      for (int mt = 0; mt < 2; ++mt)
        o[mt][hi] = __builtin_amdgcn_mfma_f32_16x16x32_bf16(
            pa[mt], bv, o[mt][hi], 0, 0, 0);
    }
  }

  // ---- out store ----
  float* og = out + ((size_t)b * NT + q0) * NH;
#pragma unroll
  for (int mi = 0; mi < 2; ++mi)
#pragma unroll
    for (int r = 0; r < 4; ++r) {
      const float inv = 1.f / lrun[mi][r];
      const int m = mi * 16 + lg * 4 + r;
#pragma unroll
      for (int hi = 0; hi < 4; ++hi)
        og[m * 64 + hi * 16 + l15] = o[mi][hi][r] * inv;
    }
}

// ---------------------------------------------------------------------------
extern "C" void kernel_launch(void* const* d_in, const int* in_sizes, int n_in,
                              void* d_out, int out_size, void* d_ws,
                              size_t ws_size, hipStream_t stream) {
  const float* x  = (const float*)d_in[0];
  const float* Wq = (const float*)d_in[1];
  const float* Wk = (const float*)d_in[2];
  const float* Wv = (const float*)d_in[3];
  unsigned short* Wt2 = (unsigned short*)d_ws;  // 147 KB, fragment-major
  float* out = (float*)d_out;

  w_prep_kernel<<<dim3((WT_ELEMS + 255) / 256), dim3(256), 0, stream>>>(
      Wq, Wk, Wv, Wt2);
  fused_qkv_attn_kernel<<<dim3(NB), dim3(512), 0, stream>>>(x, Wt2, out);
}

// Round 12
// 44.224 us; speedup vs baseline: 1.0162x; 1.0162x over previous
//
#include <hip/hip_runtime.h>
#include <hip/hip_bf16.h>

// Problem constants (B, T, C, HS) from the reference.
#define NB 256
#define NT 256
#define NC 384
#define NH 64
#define NW 192              // 3 * NH concatenated output cols
#define WT_ELEMS (NW * NC)  // Wt2 bf16 elements = 73728 (147456 B)

typedef short bf16x8 __attribute__((ext_vector_type(8)));
typedef float f32x4 __attribute__((ext_vector_type(4)));

__device__ __forceinline__ unsigned short f2bf(float f) {
  union { float f; unsigned int i; } c;
  c.f = f;
  const unsigned int r = c.i + 0x7fffu + ((c.i >> 16) & 1u);
  return (unsigned short)(r >> 16);
}

__device__ __forceinline__ unsigned short f2bf_hw(float f) {
  __hip_bfloat16 b = __float2bfloat16(f);
  return *reinterpret_cast<unsigned short*>(&b);
}

__device__ __forceinline__ bf16x8 cvt8(float4 lo, float4 hi) {
  union { bf16x8 v; unsigned short u[8]; } au;
  au.u[0] = f2bf_hw(lo.x); au.u[1] = f2bf_hw(lo.y);
  au.u[2] = f2bf_hw(lo.z); au.u[3] = f2bf_hw(lo.w);
  au.u[4] = f2bf_hw(hi.x); au.u[5] = f2bf_hw(hi.y);
  au.u[6] = f2bf_hw(hi.z); au.u[7] = f2bf_hw(hi.w);
  return au.v;
}

// ---------------------------------------------------------------------------
// Kernel 0: build FRAGMENT-MAJOR weights (unchanged from round 11).
// Wt2[((kt*12 + ni)*64 + lane)*8 + j] = W_sel[k][h]:
//   n = ni*16 + (lane&15), k = kt*32 + (lane>>4)*8 + j.
// ---------------------------------------------------------------------------
__global__ __launch_bounds__(256) void w_prep_kernel(
    const float* __restrict__ Wq,
    const float* __restrict__ Wk,
    const float* __restrict__ Wv,
    unsigned short* __restrict__ Wt2) {
  const int o = blockIdx.x * 256 + threadIdx.x;
  if (o >= WT_ELEMS) return;
  const int j = o & 7;
  const int lane = (o >> 3) & 63;
  const int fi = o >> 9;  // kt*12 + ni
  const int ni = fi % 12;
  const int kt = fi / 12;
  const int n = ni * 16 + (lane & 15);
  const int k = kt * 32 + ((lane >> 4) << 3) + j;
  const float* W = (n < 64) ? Wq : (n < 128) ? Wk : Wv;
  Wt2[o] = f2bf(W[k * NH + (n & 63)]);
}

// ---------------------------------------------------------------------------
// Kernel 1 (round 12): fused proj+attn, explicit 3-deep A-register pipeline,
// W resident in LDS.
//
// Rounds 9-11 post-mortem: staging path, barrier lockstep, and barrier-free
// all neutral at ~43 us; VGPR=92 (acc in AGPR, near-zero load lookahead)
// + observed 13 GB/s/CU => ~1-2 loads/wave in flight, duty ~20%. This
// round attacks pipeline DEPTH directly:
//   - W (full 144 KB fragment-major) staged into LDS once at kernel start;
//     proj W-reads are conflict-free ds_read_b128 (16B/lane, 2-way=free).
//   - A-tiles in 3 rotating named register sets (48 VGPR): consume tile
//     kt (issued 3 steps ago), issue kt+3. ~8 KB/wave in flight ->
//     64 KB/CU >> 22 KB Little's-law need at 900 cy HBM latency.
//   - NO barriers / explicit waitcnt in the loop; in-order consumption
//     gives compiler-counted vmcnt.
// LDS (147456 B): proj = W image; attn reuses: Kls 0 | Vtls 32K | Qls 64K
// | Pls 96K..116K (same offsets as round 11, all < 144 KB).
// mfma_f32_16x16x32_bf16 layouts (HW-verified round 2):
//   A/B: k = (l>>4)*8+j contiguous;  D: n = l&15, m = (l>>4)*4 + r.
// ---------------------------------------------------------------------------
__global__ __launch_bounds__(512, 2) void fused_qkv_attn_kernel(
    const float* __restrict__ x,
    const unsigned short* __restrict__ Wt2,
    float* __restrict__ out) {
  __shared__ __align__(16) unsigned char lds[147456];

  const int tid = threadIdx.x;
  const int w = tid >> 6;
  const int lane = tid & 63;
  const int l15 = lane & 15;
  const int lg = lane >> 4;
  const int b = blockIdx.x;
  const int row0 = b * NT;              // this block's 256 x-rows
  const int qt = (w < 4) ? w : 11 - w;  // causal-balanced q-tile per wave
  const int wbase = qt * 32;            // wave's 32 rows (block-local)

  f32x4 acc[2][12];
#pragma unroll
  for (int mi = 0; mi < 2; ++mi)
#pragma unroll
    for (int ni = 0; ni < 12; ++ni)
#pragma unroll
      for (int r = 0; r < 4; ++r) acc[mi][ni][r] = 0.f;

  // ---- stage ALL of W into LDS (18 x 16B DMA per thread, linear) ----
#pragma unroll
  for (int i = 0; i < 18; ++i) {
    const int idx = i * 512 + tid;  // 16B chunk index, 9216 total
    __builtin_amdgcn_global_load_lds(
        (const __attribute__((address_space(1))) void*)(Wt2 + idx * 8),
        (__attribute__((address_space(3))) void*)(lds + idx * 16), 16, 0, 0);
  }

  // ---- A-pipeline prologue: issue tiles 0,1,2 into sets A,B,C ----
  const float* xa0 = x + (size_t)(row0 + wbase + l15) * NC + lg * 8;
  const float* xa1 = xa0 + (size_t)16 * NC;

  float4 aA0, aA1, aA2, aA3, aB0, aB1, aB2, aB3, aC0, aC1, aC2, aC3;

#define LOADA(S, KT)                                                          \
  do {                                                                        \
    a##S##0 = *reinterpret_cast<const float4*>(xa0 + (KT)*32);                \
    a##S##1 = *reinterpret_cast<const float4*>(xa0 + (KT)*32 + 4);            \
    a##S##2 = *reinterpret_cast<const float4*>(xa1 + (KT)*32);                \
    a##S##3 = *reinterpret_cast<const float4*>(xa1 + (KT)*32 + 4);            \
  } while (0)

  LOADA(A, 0);
  LOADA(B, 1);
  LOADA(C, 2);

  // Retire the 18 W-DMA loads (A sets may stay in flight: 12 outstanding).
  asm volatile("s_waitcnt vmcnt(12)" ::: "memory");
  __builtin_amdgcn_s_barrier();

  // ---- proj loop: consume set, refill 3 ahead; W from LDS ----
  const unsigned short* Wl =
      reinterpret_cast<const unsigned short*>(lds) + lane * 8;

#define STEP(S, KT)                                                           \
  do {                                                                        \
    const bf16x8 afr0 = cvt8(a##S##0, a##S##1);                               \
    const bf16x8 afr1 = cvt8(a##S##2, a##S##3);                               \
    if ((KT) + 3 < 12) LOADA(S, (KT) + 3);                                    \
    _Pragma("unroll") for (int ni = 0; ni < 12; ++ni) {                       \
      const bf16x8 bfr = *reinterpret_cast<const bf16x8*>(                    \
          Wl + (size_t)((KT)*12 + ni) * 512);                                 \
      acc[0][ni] = __builtin_amdgcn_mfma_f32_16x16x32_bf16(                   \
          afr0, bfr, acc[0][ni], 0, 0, 0);                                    \
      acc[1][ni] = __builtin_amdgcn_mfma_f32_16x16x32_bf16(                   \
          afr1, bfr, acc[1][ni], 0, 0, 0);                                    \
    }                                                                         \
  } while (0)

  STEP(A, 0);  STEP(B, 1);  STEP(C, 2);
  STEP(A, 3);  STEP(B, 4);  STEP(C, 5);
  STEP(A, 6);  STEP(B, 7);  STEP(C, 8);
  STEP(A, 9);  STEP(B, 10); STEP(C, 11);

  // All waves done reading the W image before overwriting LDS with K/V/Q.
  __syncthreads();

  // ---- epilogue: scatter acc into attention LDS layouts (bf16) ----
  unsigned short* Kls = reinterpret_cast<unsigned short*>(lds);           // 32K
  unsigned short* Vtls = reinterpret_cast<unsigned short*>(lds + 32768);  // 32K
  unsigned short* Qls = reinterpret_cast<unsigned short*>(lds + 65536);   // 32K
  unsigned short* Pls = reinterpret_cast<unsigned short*>(lds + 98304);   // 20K

#pragma unroll
  for (int mi = 0; mi < 2; ++mi)
#pragma unroll
    for (int ni = 0; ni < 12; ++ni) {
      const int n = ni * 16 + l15;
#pragma unroll
      for (int r = 0; r < 4; ++r) {
        const int srow = wbase + mi * 16 + lg * 4 + r;
        const unsigned short val = f2bf_hw(acc[mi][ni][r]);
        if (ni < 4) {
          Qls[srow * 64 + (n ^ ((srow & 7) << 3))] = val;
        } else if (ni < 8) {
          const int h = n - 64;
          Kls[srow * 64 + (h ^ ((srow & 7) << 3))] = val;
        } else {
          const int h = n - 128;
          Vtls[h * 256 + (srow ^ ((h & 7) << 3))] = val;
        }
      }
    }
  __syncthreads();

  // ---- attention phase (flash, per-wave independent; unchanged) ----
  const int q0 = wbase;
  bf16x8 a_q[2][2];
#pragma unroll
  for (int mi = 0; mi < 2; ++mi)
#pragma unroll
    for (int ks = 0; ks < 2; ++ks) {
      const int srow = q0 + mi * 16 + l15;
      a_q[mi][ks] = *reinterpret_cast<const bf16x8*>(
          Qls + srow * 64 + ((ks * 32 + lg * 8) ^ ((srow & 7) << 3)));
    }

  f32x4 o[2][4];
  float mrun[2][4], lrun[2][4];
#pragma unroll
  for (int mi = 0; mi < 2; ++mi)
#pragma unroll
    for (int r = 0; r < 4; ++r) {
      mrun[mi][r] = -3.0e38f;
      lrun[mi][r] = 0.f;
#pragma unroll
      for (int hi = 0; hi < 4; ++hi) o[mi][hi][r] = 0.f;
    }

  unsigned short* Pw = Pls + w * 1280;  // per-wave [32][40]

  for (int j = 0; j <= qt; ++j) {
    f32x4 s_acc[2][2];
#pragma unroll
    for (int mi = 0; mi < 2; ++mi)
#pragma unroll
      for (int si = 0; si < 2; ++si)
#pragma unroll
        for (int r = 0; r < 4; ++r) s_acc[mi][si][r] = 0.f;

#pragma unroll
    for (int ks = 0; ks < 2; ++ks) {
      bf16x8 bk[2];
#pragma unroll
      for (int si = 0; si < 2; ++si) {
        const int srow = j * 32 + si * 16 + l15;
        const int kel = ks * 32 + lg * 8;
        bk[si] = *reinterpret_cast<const bf16x8*>(
            Kls + srow * 64 + (kel ^ ((srow & 7) << 3)));
      }
#pragma unroll
      for (int mi = 0; mi < 2; ++mi)
#pragma unroll
        for (int si = 0; si < 2; ++si)
          s_acc[mi][si] = __builtin_amdgcn_mfma_f32_16x16x32_bf16(
              a_q[mi][ks], bk[si], s_acc[mi][si], 0, 0, 0);
    }

    const bool diag = (j == qt);
#pragma unroll
    for (int mi = 0; mi < 2; ++mi) {
#pragma unroll
      for (int r = 0; r < 4; ++r) {
        const int mloc = mi * 16 + lg * 4 + r;
        float v0 = s_acc[mi][0][r] * 0.125f;
        float v1 = s_acc[mi][1][r] * 0.125f;
        if (diag) {
          if (l15 > mloc) v0 = -3.0e38f;
          if (16 + l15 > mloc) v1 = -3.0e38f;
        }
        float pm = fmaxf(v0, v1);
        pm = fmaxf(pm, __shfl_xor(pm, 1, 16));
        pm = fmaxf(pm, __shfl_xor(pm, 2, 16));
        pm = fmaxf(pm, __shfl_xor(pm, 4, 16));
        pm = fmaxf(pm, __shfl_xor(pm, 8, 16));
        const float mnew = fmaxf(mrun[mi][r], pm);
        const float alpha = __expf(mrun[mi][r] - mnew);
        mrun[mi][r] = mnew;
        const float p0 = __expf(v0 - mnew);
        const float p1 = __expf(v1 - mnew);
        float ps = p0 + p1;
        ps += __shfl_xor(ps, 1, 16);
        ps += __shfl_xor(ps, 2, 16);
        ps += __shfl_xor(ps, 4, 16);
        ps += __shfl_xor(ps, 8, 16);
        lrun[mi][r] = lrun[mi][r] * alpha + ps;
#pragma unroll
        for (int hi = 0; hi < 4; ++hi) o[mi][hi][r] *= alpha;
        Pw[mloc * 40 + l15] = f2bf(p0);
        Pw[mloc * 40 + 16 + l15] = f2bf(p1);
      }
    }

    bf16x8 pa[2];
#pragma unroll
    for (int mt = 0; mt < 2; ++mt)
      pa[mt] = *reinterpret_cast<const bf16x8*>(
          Pw + (mt * 16 + l15) * 40 + lg * 8);
#pragma unroll
    for (int hi = 0; hi < 4; ++hi) {
      const int h = hi * 16 + l15;
      const int sel = j * 32 + lg * 8;
      const bf16x8 bv = *reinterpret_cast<const bf16x8*>(
          Vtls + h * 256 + (sel ^ ((h & 7) << 3)));
#pragma unroll
      for (int mt = 0; mt < 2; ++mt)
        o[mt][hi] = __builtin_amdgcn_mfma_f32_16x16x32_bf16(
            pa[mt], bv, o[mt][hi], 0, 0, 0);
    }
  }

  // ---- out store ----
  float* og = out + ((size_t)b * NT + q0) * NH;
#pragma unroll
  for (int mi = 0; mi < 2; ++mi)
#pragma unroll
    for (int r = 0; r < 4; ++r) {
      const float inv = 1.f / lrun[mi][r];
      const int m = mi * 16 + lg * 4 + r;
#pragma unroll
      for (int hi = 0; hi < 4; ++hi)
        og[m * 64 + hi * 16 + l15] = o[mi][hi][r] * inv;
    }
}

// ---------------------------------------------------------------------------
extern "C" void kernel_launch(void* const* d_in, const int* in_sizes, int n_in,
                              void* d_out, int out_size, void* d_ws,
                              size_t ws_size, hipStream_t stream) {
  const float* x  = (const float*)d_in[0];
  const float* Wq = (const float*)d_in[1];
  const float* Wk = (const float*)d_in[2];
  const float* Wv = (const float*)d_in[3];
  unsigned short* Wt2 = (unsigned short*)d_ws;  // 147 KB, fragment-major
  float* out = (float*)d_out;

  w_prep_kernel<<<dim3((WT_ELEMS + 255) / 256), dim3(256), 0, stream>>>(
      Wq, Wk, Wv, Wt2);
  fused_qkv_attn_kernel<<<dim3(NB), dim3(512), 0, stream>>>(x, Wt2, out);
}